// Round 1
// 312.495 us; speedup vs baseline: 1.2039x; 1.2039x over previous
//
#include <hip/hip_runtime.h>
#include <hip/hip_bf16.h>

// Model_81956565942963: TCN + low-rank dynamic graph + linear head.
// B=16, L=512, N=64, D=128, S=32 x 16, r=8, P=96. f32 in/out.
// R13: layer-1 conv collapsed to rank-1 form. Embedding is
//   h[l,ci] = x[l]*we[ci]+be[ci]  (rank-1 in ci), so
//   y1[l,co] = sum_k x[l+k-2]*A[k,co] + Bias3[min(l,2),co],
//   A[k,co] = sum_ci we[ci]*w0[k,ci,co]  (precomputed in wt_prep).
// This removes 120 of 216 MFMAs/wave, the 82x136 embed LDS buffer, the
// layer-1 fragment reads and the layer-1 epilogue LDS round-trip.
// h2 staging tile aliases h1s (residuals pulled to regs first), LDS 40KB->21KB.
// e1/e2 tail parallelized 4-way over d + shfl reduce.

#define BATCH 16
#define SEQ 512
#define NVAR 64
#define DM 128
#define SEG 32
#define SCL 16
#define RNK 8
#define PRED 96
#define BN (BATCH * NVAR)   // 1024
#define ROWLEN (SEQ * DM)   // 65536

typedef unsigned short ushort_t;
typedef __attribute__((ext_vector_type(8))) short short8;   // 8 bf16
typedef __attribute__((ext_vector_type(4))) float f32x4;

__device__ inline float bf2f(ushort_t u) {
    union { unsigned int i; float f; } x;
    x.i = ((unsigned int)u) << 16;
    return x.f;
}
__device__ inline ushort_t f2bf(float f) {
    union { float f; unsigned int i; } u;
    u.f = f;
    unsigned int x = u.i;
    return (ushort_t)((x + 0x7fffu + ((x >> 16) & 1u)) >> 16);  // RNE
}
__device__ inline unsigned int pkbf(float a, float b) {  // packed bf16 pair
    __hip_bfloat162 h = __float22bfloat162_rn(make_float2(a, b));
    union { __hip_bfloat162 h2; unsigned int u; } c;
    c.h2 = h;
    return c.u;
}
__device__ inline float blo(unsigned int u) {
    union { unsigned int i; float f; } x;
    x.i = u << 16;
    return x.f;
}
__device__ inline float bhi(unsigned int u) {
    union { unsigned int i; float f; } x;
    x.i = u & 0xFFFF0000u;
    return x.f;
}
// gelu(x) = x * sigmoid(2t); rcp is v_rcp_f32 (1 inst) not the div sequence
__device__ inline float gelu_fast(float x) {
    float t = 0.7978845608028654f * x * (1.0f + 0.044715f * x * x);
    float e = __expf(-2.0f * t);
    return x * __builtin_amdgcn_rcpf(1.0f + e);
}

// ---------------- weight prep ----------------------------------------------
// bx in [0,3): layer-2 tap bx -> frag-major bf16 WTf (by=ci, tid=co).
// bx==3, by==0: rank-1 collapse of layer-1: A[k][co], Bias3[j][co]
//   (j = number-of-valid-taps bias: j = min(l,2)).
__global__ __launch_bounds__(128) void wt_prep(
    const float* __restrict__ conv_w, const float* __restrict__ w_emb,
    const float* __restrict__ b_emb, const float* __restrict__ conv_b,
    ushort_t* __restrict__ WTf, float* __restrict__ Acoef,
    float* __restrict__ Bias3, float* __restrict__ regacc) {
    if (blockIdx.x == 0 && blockIdx.y == 0 && threadIdx.x == 0) regacc[0] = 0.f;
    if (blockIdx.x < 3) {
        int tap = blockIdx.x;   // layer-2 tap
        int ci = blockIdx.y;    // 0..127
        int co = threadIdx.x;   // 0..127
        int kt = ci >> 5, quad = (ci >> 3) & 3, j = ci & 7;
        int ng = co >> 4, col = co & 15;
        int lane = quad * 16 + col;
        WTf[((((size_t)tap * 4 + kt) * 8 + ng) * 64 + lane) * 8 + j] =
            f2bf(conv_w[(size_t)(3 + tap) * 16384 + (size_t)ci * 128 + co]);
    } else if (blockIdx.y == 0) {
        int co = threadIdx.x;
        float a0 = 0.f, a1 = 0.f, a2 = 0.f, c0 = 0.f, c1 = 0.f, c2 = 0.f;
        for (int ci = 0; ci < 128; ++ci) {
            float we = w_emb[ci], be = b_emb[ci];
            float w0 = conv_w[((size_t)(0 * 128 + ci)) * 128 + co];
            float w1 = conv_w[((size_t)(1 * 128 + ci)) * 128 + co];
            float w2 = conv_w[((size_t)(2 * 128 + ci)) * 128 + co];
            a0 += we * w0; c0 += be * w0;
            a1 += we * w1; c1 += be * w1;
            a2 += we * w2; c2 += be * w2;
        }
        Acoef[0 * 128 + co] = a0;
        Acoef[1 * 128 + co] = a1;
        Acoef[2 * 128 + co] = a2;
        float b0 = conv_b[co];
        Bias3[0 * 128 + co] = b0 + c2;             // l==0: only tap k=2 valid
        Bias3[1 * 128 + co] = b0 + c1 + c2;        // l==1: taps k=1,2 valid
        Bias3[2 * 128 + co] = b0 + c0 + c1 + c2;   // l>=2: all taps valid
    }
}

// ---------------- fused TCN (layer1 scalar + layer2 MFMA) + z + e1/e2 ------
__global__ __launch_bounds__(256, 4) void tcn_mfma(
    const float* __restrict__ x, const float* __restrict__ w_emb,
    const float* __restrict__ b_emb, const float* __restrict__ Acoef,
    const float* __restrict__ Bias3, const ushort_t* __restrict__ WTf,
    const float* __restrict__ conv_b,
    const float* __restrict__ gw1, const float* __restrict__ gb1,
    const float* __restrict__ gw2, const float* __restrict__ gb2,
    ushort_t* __restrict__ h2, float* __restrict__ e1, float* __restrict__ e2) {
    __shared__ __align__(16) ushort_t h1s[68 * 136];  // h1, row = li+4; later
                                                      // rows 0..63 = staged h2
    __shared__ float xs[70];                          // x[l0-6 .. l0+63]
    __shared__ float zbuf[4 * 128];                   // segment means

    int bn = blockIdx.x;
    int b = bn >> 6, n = bn & 63;
    int chunk = blockIdx.y;
    int l0 = chunk * 64;
    int tid = threadIdx.x;

    // ---- stage x halo (broadcast scalars) ----
    {
        const float* xb = x + (size_t)b * SEQ * NVAR + n;
        if (tid < 70) {
            int l = l0 - 6 + tid;
            xs[tid] = (l >= 0) ? xb[(size_t)l * NVAR] : 0.0f;
        }
    }
    __syncthreads();

    // ---- layer 1 direct: h1[row][d] = gelu(sum_k x*A) + (x*we+be) ----
    {
        int dp = (tid & 63) * 2;
        float2 A0 = *reinterpret_cast<const float2*>(&Acoef[0 * 128 + dp]);
        float2 A1 = *reinterpret_cast<const float2*>(&Acoef[1 * 128 + dp]);
        float2 A2 = *reinterpret_cast<const float2*>(&Acoef[2 * 128 + dp]);
        float2 BF = *reinterpret_cast<const float2*>(&Bias3[2 * 128 + dp]);
        float2 we2 = *reinterpret_cast<const float2*>(&w_emb[dp]);
        float2 be2 = *reinterpret_cast<const float2*>(&b_emb[dp]);
#pragma unroll
        for (int i = 0; i < 17; ++i) {  // 68 rows x 64 pairs = 17*256
            int row = (tid >> 6) + 4 * i;   // wave-uniform
            int l = l0 - 4 + row;
            unsigned int pk = 0;
            if (l >= 0) {
                float x0 = xs[row], x1 = xs[row + 1], x2 = xs[row + 2];
                float2 bias = BF;
                if (l < 2)  // chunk 0, rows 4/5 only (wave-uniform)
                    bias = *reinterpret_cast<const float2*>(&Bias3[l * 128 + dp]);
                float y0 = fmaf(x0, A0.x, fmaf(x1, A1.x, fmaf(x2, A2.x, bias.x)));
                float y1 = fmaf(x0, A0.y, fmaf(x1, A1.y, fmaf(x2, A2.y, bias.y)));
                float r0 = gelu_fast(y0) + fmaf(x2, we2.x, be2.x);
                float r1 = gelu_fast(y1) + fmaf(x2, we2.y, be2.y);
                pk = pkbf(r0, r1);
            }
            *reinterpret_cast<unsigned int*>(&h1s[row * 136 + dp]) = pk;
        }
    }
    __syncthreads();

    int lane = tid & 63;
    int wv = tid >> 6;
    int quad = lane >> 4;
    int col = lane & 15;
    int cobase = wv * 32;

    // ---- layer 2 MFMA: li = mt*16+col; tap t reads h1s row li+2t+4-4 = li+2t ----
    f32x4 acc2[4][2];
#pragma unroll
    for (int mt = 0; mt < 4; ++mt)
#pragma unroll
        for (int nt = 0; nt < 2; ++nt)
            acc2[mt][nt] = (f32x4){0.f, 0.f, 0.f, 0.f};

#pragma unroll
    for (int tap = 0; tap < 3; ++tap) {
        short8 wf0[4], wf1[4];
#pragma unroll
        for (int kt = 0; kt < 4; ++kt) {
            const ushort_t* bp =
                WTf + ((((size_t)tap * 4 + kt) * 8 + wv * 2) * 64 + lane) * 8;
            wf0[kt] = *(const short8*)bp;
            wf1[kt] = *(const short8*)(bp + 512);
        }
#pragma unroll
        for (int kt = 0; kt < 4; ++kt) {
            int kc = kt * 32 + quad * 8;
#pragma unroll
            for (int mt = 0; mt < 4; ++mt) {
                short8 hf = *(const short8*)&h1s[(mt * 16 + col + 2 * tap) * 136 + kc];
                acc2[mt][0] = __builtin_amdgcn_mfma_f32_16x16x32_bf16(wf0[kt], hf, acc2[mt][0], 0, 0, 0);
                acc2[mt][1] = __builtin_amdgcn_mfma_f32_16x16x32_bf16(wf1[kt], hf, acc2[mt][1], 0, 0, 0);
            }
        }
    }

    // ---- epilogue 2: residuals -> regs, barrier, then stage h2 into h1s ----
    {
        uint2 res[4][2];
#pragma unroll
        for (int mt = 0; mt < 4; ++mt) {
            int li = mt * 16 + col;
#pragma unroll
            for (int nt = 0; nt < 2; ++nt) {
                int co = cobase + nt * 16 + quad * 4;
                res[mt][nt] = *reinterpret_cast<const uint2*>(
                    &h1s[(li + 4) * 136 + co]);
            }
        }
        __syncthreads();  // all h1 reads done; h1s rows 0..63 become h2 stage
        float4 bias[2];
        bias[0] = *reinterpret_cast<const float4*>(&conv_b[DM + cobase + quad * 4]);
        bias[1] = *reinterpret_cast<const float4*>(&conv_b[DM + cobase + 16 + quad * 4]);
#pragma unroll
        for (int mt = 0; mt < 4; ++mt) {
            int li = mt * 16 + col;
#pragma unroll
            for (int nt = 0; nt < 2; ++nt) {
                int co = cobase + nt * 16 + quad * 4;
                float h0 = gelu_fast(acc2[mt][nt][0] + bias[nt].x) + blo(res[mt][nt].x);
                float h1 = gelu_fast(acc2[mt][nt][1] + bias[nt].y) + bhi(res[mt][nt].x);
                float h2v = gelu_fast(acc2[mt][nt][2] + bias[nt].z) + blo(res[mt][nt].y);
                float h3 = gelu_fast(acc2[mt][nt][3] + bias[nt].w) + bhi(res[mt][nt].y);
                uint2 pk;
                pk.x = pkbf(h0, h1);
                pk.y = pkbf(h2v, h3);
                *reinterpret_cast<uint2*>(&h1s[li * 136 + co]) = pk;
            }
        }
    }
    __syncthreads();

    // ---- coalesced h2 store (from h1s rows 0..63) ----
    {
        ushort_t* orow = h2 + (size_t)bn * ROWLEN + (size_t)l0 * 128;
#pragma unroll
        for (int i = 0; i < 4; ++i) {
            int q = tid + 256 * i;
            int row = q >> 4, c8 = (q & 15) * 8;
            *(short8*)&orow[row * 128 + c8] = *(const short8*)&h1s[row * 136 + c8];
        }
    }
    // ---- z: 4 segment means over staged h2 tile ----
    {
        int d = tid & 127, sg = tid >> 7;
#pragma unroll
        for (int t = 0; t < 2; ++t) {
            int sl = sg + 2 * t;
            float a = 0.0f;
#pragma unroll
            for (int c = 0; c < SCL; ++c)
                a += bf2f(h1s[(sl * 16 + c) * 136 + d]);
            zbuf[sl * 128 + d] = a * (1.0f / 16.0f);
        }
    }
    __syncthreads();
    // ---- e1/e2: 64 outputs x 4-way d-split + shfl reduce ----
    {
        int out = tid >> 2;          // (sl, which, r)
        int part = tid & 3;          // d quarter
        int sl = out >> 4;
        int which = (out >> 3) & 1;
        int r = out & 7;
        const float* w = which ? gw2 : gw1;
        float a = 0.0f;
        int d0 = part * 32;
        for (int d = d0; d < d0 + 32; ++d)
            a += zbuf[sl * 128 + d] * w[d * RNK + r];
        a += __shfl_xor(a, 1, 64);
        a += __shfl_xor(a, 2, 64);
        if (part == 0) {
            a += (which ? gb2 : gb1)[r];
            int s = chunk * 4 + sl;
            (which ? e2 : e1)[(((size_t)b * SEG + s) * NVAR + n) * RNK + r] = a;
        }
    }
}

// ---------------- G GEMM (MFMA): split-K x2, register-prefetch pipeline -----
__global__ __launch_bounds__(256) void g_gemm(
    const ushort_t* __restrict__ h2, const float* __restrict__ head_w,
    float* __restrict__ G) {
    __shared__ __align__(16) ushort_t As[64 * 72];  // [bn][k]
    __shared__ __align__(16) ushort_t Bs[96 * 72];  // [p][k]
    int s = blockIdx.x;
    int bnt = blockIdx.y;
    int kh = blockIdx.z;
    int bn0 = bnt * 64;
    int kbase = kh * 1024;
    int lane = threadIdx.x & 63, wv = threadIdx.x >> 6;
    int quad = lane >> 4, col = lane & 15;
    int mh = wv & 1;   // bn half (32)
    int ph = wv >> 1;  // p half (48)

    int arow = threadIdx.x >> 2, akq = (threadIdx.x & 3) * 16;
    const ushort_t* aptr =
        h2 + (size_t)(bn0 + arow) * ROWLEN + (size_t)s * 2048 + kbase + akq;
    const float* bbase = head_w + ((size_t)s * 2048 + kbase) * PRED;
    int bp0[3], bk2[3];
#pragma unroll
    for (int i = 0; i < 3; ++i) {
        int q = threadIdx.x + 256 * i;
        bp0[i] = (q % 24) * 4;
        bk2[i] = (q / 24) * 2;
    }

    f32x4 acc[3][2];  // [p-tile][bn-tile]
#pragma unroll
    for (int i = 0; i < 3; ++i)
#pragma unroll
        for (int j = 0; j < 2; ++j) acc[i][j] = (f32x4){0.f, 0.f, 0.f, 0.f};

    // ---- prefetch chunk 0 ----
    short8 pa0 = *(const short8*)aptr;
    short8 pa1 = *(const short8*)(aptr + 8);
    float4 pb0[3], pb1[3];
#pragma unroll
    for (int i = 0; i < 3; ++i) {
        const float* src = bbase + (size_t)bk2[i] * PRED + bp0[i];
        pb0[i] = *reinterpret_cast<const float4*>(src);
        pb1[i] = *reinterpret_cast<const float4*>(src + PRED);
    }
    *(short8*)&As[arow * 72 + akq] = pa0;
    *(short8*)&As[arow * 72 + akq + 8] = pa1;
#pragma unroll
    for (int i = 0; i < 3; ++i) {
        *reinterpret_cast<unsigned int*>(&Bs[(bp0[i] + 0) * 72 + bk2[i]]) = pkbf(pb0[i].x, pb1[i].x);
        *reinterpret_cast<unsigned int*>(&Bs[(bp0[i] + 1) * 72 + bk2[i]]) = pkbf(pb0[i].y, pb1[i].y);
        *reinterpret_cast<unsigned int*>(&Bs[(bp0[i] + 2) * 72 + bk2[i]]) = pkbf(pb0[i].z, pb1[i].z);
        *reinterpret_cast<unsigned int*>(&Bs[(bp0[i] + 3) * 72 + bk2[i]]) = pkbf(pb0[i].w, pb1[i].w);
    }
    __syncthreads();

    for (int kt = 0; kt < 16; ++kt) {
        if (kt < 15) {
            const ushort_t* ap = aptr + (kt + 1) * 64;
            pa0 = *(const short8*)ap;
            pa1 = *(const short8*)(ap + 8);
#pragma unroll
            for (int i = 0; i < 3; ++i) {
                const float* src =
                    bbase + (size_t)((kt + 1) * 64 + bk2[i]) * PRED + bp0[i];
                pb0[i] = *reinterpret_cast<const float4*>(src);
                pb1[i] = *reinterpret_cast<const float4*>(src + PRED);
            }
        }
#pragma unroll
        for (int kk = 0; kk < 2; ++kk) {
            int kc = kk * 32 + quad * 8;
            short8 pfr[3];
#pragma unroll
            for (int i = 0; i < 3; ++i)
                pfr[i] = *(const short8*)&Bs[(ph * 48 + i * 16 + col) * 72 + kc];
#pragma unroll
            for (int j = 0; j < 2; ++j) {
                short8 bnfr = *(const short8*)&As[(mh * 32 + j * 16 + col) * 72 + kc];
#pragma unroll
                for (int i = 0; i < 3; ++i)
                    acc[i][j] = __builtin_amdgcn_mfma_f32_16x16x32_bf16(pfr[i], bnfr, acc[i][j], 0, 0, 0);
            }
        }
        __syncthreads();
        if (kt < 15) {
            *(short8*)&As[arow * 72 + akq] = pa0;
            *(short8*)&As[arow * 72 + akq + 8] = pa1;
#pragma unroll
            for (int i = 0; i < 3; ++i) {
                *reinterpret_cast<unsigned int*>(&Bs[(bp0[i] + 0) * 72 + bk2[i]]) = pkbf(pb0[i].x, pb1[i].x);
                *reinterpret_cast<unsigned int*>(&Bs[(bp0[i] + 1) * 72 + bk2[i]]) = pkbf(pb0[i].y, pb1[i].y);
                *reinterpret_cast<unsigned int*>(&Bs[(bp0[i] + 2) * 72 + bk2[i]]) = pkbf(pb0[i].z, pb1[i].z);
                *reinterpret_cast<unsigned int*>(&Bs[(bp0[i] + 3) * 72 + bk2[i]]) = pkbf(pb0[i].w, pb1[i].w);
            }
            __syncthreads();
        }
    }
    // atomic accumulate G[s][b][p][m] (two kh blocks per output)
    int b = bnt;
#pragma unroll
    for (int i = 0; i < 3; ++i)
#pragma unroll
        for (int j = 0; j < 2; ++j)
#pragma unroll
            for (int r = 0; r < 4; ++r) {
                int p = ph * 48 + i * 16 + quad * 4 + r;
                int m = mh * 32 + j * 16 + col;
                atomicAdd(&G[(((size_t)s * BATCH + b) * PRED + p) * NVAR + m],
                          acc[i][j][r]);
            }
}

// ---------------- out partials (+ fused softmax + regularizer) --------------
__global__ __launch_bounds__(256) void out_partial(
    const float* __restrict__ e1, const float* __restrict__ e2,
    const float* __restrict__ G, float* __restrict__ partial,
    float* __restrict__ regacc) {
    __shared__ float adjn[2][32][65];
    __shared__ float Gs[96][65];
    __shared__ float e2s[3][64][8];
    __shared__ float e1s[3][32][8];
    __shared__ float wsum[4];
    int b = blockIdx.x, sg = blockIdx.y, nh = blockIdx.z;
    int s0 = sg * 2;
    int wv = threadIdx.x >> 6, lane = threadIdx.x & 63;

    // stage e1/e2 slices for s = s0-1, s0, s0+1 (zero-fill s<0)
    for (int idx = threadIdx.x; idx < 3 * 64 * 8; idx += 256) {
        int j = idx >> 9, m = (idx >> 3) & 63, r = idx & 7;
        int s = s0 - 1 + j;
        e2s[j][m][r] = (s >= 0)
            ? e2[(((size_t)b * SEG + s) * NVAR + m) * RNK + r] : 0.0f;
    }
    for (int idx = threadIdx.x; idx < 3 * 32 * 8; idx += 256) {
        int j = idx >> 8, nl = (idx >> 3) & 31, r = idx & 7;
        int s = s0 - 1 + j;
        e1s[j][nl][r] = (s >= 0)
            ? e1[(((size_t)b * SEG + s) * NVAR + nh * 32 + nl) * RNK + r] : 0.0f;
    }
    __syncthreads();

    // compute adj rows (lane = m); wave wv handles rows wv*8..wv*8+7
    float regsum = 0.0f;
    for (int t = 0; t < 8; ++t) {
        int nl = wv * 8 + t;
        float a[3];
#pragma unroll
        for (int j = 0; j < 3; ++j) {
            float sc = 0.0f;
#pragma unroll
            for (int r = 0; r < 8; ++r) sc += e1s[j][nl][r] * e2s[j][lane][r];
            sc *= 0.35355339059327373f;  // 1/sqrt(8)
            float mx = sc;
            for (int off = 32; off; off >>= 1)
                mx = fmaxf(mx, __shfl_xor(mx, off, 64));
            float ex = __expf(sc - mx);
            float sm = ex;
            for (int off = 32; off; off >>= 1) sm += __shfl_xor(sm, off, 64);
            a[j] = ex * __builtin_amdgcn_rcpf(sm);
        }
        if (s0 > 0) regsum += fabsf(a[1] - a[0]);  // diff at s0 (vs s0-1)
        regsum += fabsf(a[2] - a[1]);              // diff at s0+1 (vs s0)
        adjn[0][nl][lane] = a[1];
        adjn[1][nl][lane] = a[2];
    }
    __syncthreads();

    int pg = threadIdx.x >> 4;   // p = pg*6 + j
    int ng = threadIdx.x & 15;   // n = nh*32 + ng*2 + i
    float acc[6][2];
#pragma unroll
    for (int j = 0; j < 6; ++j) { acc[j][0] = 0.f; acc[j][1] = 0.f; }

#pragma unroll
    for (int ss = 0; ss < 2; ++ss) {
        int s = s0 + ss;
#pragma unroll
        for (int i = 0; i < 6; ++i) {
            int q = threadIdx.x + 256 * i;
            int row = q >> 4, mq = (q & 15) * 4;
            float4 v = *reinterpret_cast<const float4*>(
                &G[(((size_t)s * BATCH + b) * PRED + row) * NVAR + mq]);
            Gs[row][mq + 0] = v.x; Gs[row][mq + 1] = v.y;
            Gs[row][mq + 2] = v.z; Gs[row][mq + 3] = v.w;
        }
        __syncthreads();
#pragma unroll 4
        for (int m = 0; m < 64; ++m) {
            float a0 = adjn[ss][ng * 2 + 0][m];
            float a1 = adjn[ss][ng * 2 + 1][m];
#pragma unroll
            for (int j = 0; j < 6; ++j) {
                float g = Gs[pg * 6 + j][m];
                acc[j][0] += g * a0;
                acc[j][1] += g * a1;
            }
        }
        __syncthreads();
    }
#pragma unroll
    for (int j = 0; j < 6; ++j)
#pragma unroll
        for (int i = 0; i < 2; ++i) {
            int p = pg * 6 + j, n = nh * 32 + ng * 2 + i;
            partial[(((size_t)sg * BATCH + b) * PRED + p) * NVAR + n] = acc[j][i];
        }
    // block-reduce regsum -> one atomic
    for (int off = 32; off; off >>= 1) regsum += __shfl_xor(regsum, off, 64);
    if (lane == 0) wsum[wv] = regsum;
    __syncthreads();
    if (threadIdx.x == 0)
        atomicAdd(regacc, wsum[0] + wsum[1] + wsum[2] + wsum[3]);
}

// ---------------- reduce 16 partials + head_b (float4); write reg -----------
__global__ __launch_bounds__(256) void out_reduce(
    const float* __restrict__ partial, const float* __restrict__ head_b,
    const float* __restrict__ regacc, float* __restrict__ out, int out_size) {
    int i4 = blockIdx.x * 256 + threadIdx.x;  // 0..24575 float4s
    int p = (i4 >> 4) % PRED;
    float hb = head_b[p];
    float4 a = make_float4(hb, hb, hb, hb);
    const int stride4 = BATCH * PRED * NVAR / 4;
    const float4* p4 = reinterpret_cast<const float4*>(partial);
#pragma unroll
    for (int sg = 0; sg < 16; ++sg) {
        float4 v = p4[sg * stride4 + i4];
        a.x += v.x; a.y += v.y; a.z += v.z; a.w += v.w;
    }
    reinterpret_cast<float4*>(out)[i4] = a;
    if (i4 == 0) out[out_size - 1] = regacc[0] * (1.0f / 65536.0f);
}

extern "C" void kernel_launch(void* const* d_in, const int* in_sizes, int n_in,
                              void* d_out, int out_size, void* d_ws,
                              size_t ws_size, hipStream_t stream) {
    const float* x_enc  = (const float*)d_in[0];
    const float* w_emb  = (const float*)d_in[4];
    const float* b_emb  = (const float*)d_in[5];
    const float* conv_w = (const float*)d_in[6];
    const float* conv_b = (const float*)d_in[7];
    const float* gg_w1  = (const float*)d_in[8];
    const float* gg_b1  = (const float*)d_in[9];
    const float* gg_w2  = (const float*)d_in[10];
    const float* gg_b2  = (const float*)d_in[11];
    const float* head_w = (const float*)d_in[12];
    const float* head_b = (const float*)d_in[13];
    float* out = (float*)d_out;

    // workspace: 157,286,404 B total. WTf (layer-2 only, 98,304 B) + A/Bias3
    // live in the former WTf slot; partial overlaps h2 (dead after g_gemm).
    char* ws = (char*)d_ws;
    ushort_t* h2   = (ushort_t*)(ws);                   // 134,217,728
    float* partial = (float*)(ws);                      //   6,291,456 (overlaps h2)
    float* G       = (float*)(ws + 134217728);          //  12,582,912
    float* e1      = (float*)(ws + 146800640);          //   1,048,576
    float* e2      = (float*)(ws + 147849216);          //   1,048,576
    ushort_t* WTf  = (ushort_t*)(ws + 148897792);       //      98,304
    float* Acoef   = (float*)(ws + 148996096);          //       1,536
    float* Bias3   = (float*)(ws + 148997632);          //       1,536
    float* regacc  = (float*)(ws + 157286400);          //           4

    hipMemsetAsync(G, 0, 12582912, stream);  // zero G for split-K atomics
    wt_prep<<<dim3(4, 128), 128, 0, stream>>>(
        conv_w, w_emb, b_emb, conv_b, WTf, Acoef, Bias3, regacc);
    tcn_mfma<<<dim3(BN, SEQ / 64), 256, 0, stream>>>(
        x_enc, w_emb, b_emb, Acoef, Bias3, WTf, conv_b,
        gg_w1, gg_b1, gg_w2, gg_b2, h2, e1, e2);
    g_gemm<<<dim3(SEG, BATCH, 2), 256, 0, stream>>>(h2, head_w, G);
    out_partial<<<dim3(BATCH, 16, 2), 256, 0, stream>>>(
        e1, e2, G, partial, regacc);
    out_reduce<<<BATCH * PRED * NVAR / 1024, 256, 0, stream>>>(
        partial, head_b, regacc, out, out_size);
}

// Round 2
// 297.108 us; speedup vs baseline: 1.2662x; 1.0518x over previous
//
#include <hip/hip_runtime.h>
#include <hip/hip_bf16.h>

// Model_81956565942963: TCN + low-rank dynamic graph + linear head.
// B=16, L=512, N=64, D=128, S=32 x 16, r=8, P=96. f32 in/out.
// R14:
//  - g_gemm v2: head_w pre-transposed to bf16 fragment-major (hw_prep, per-kh
//    half due to ws budget); B fragments loaded b128 direct from global (L2),
//    Bs LDS + in-loop pkbf staging eliminated; As double-buffered with ONE
//    barrier per k-tile; B frags software-pipelined 1 tile ahead; split-K via
//    two launches (store / read-add) -> no atomics, no memset.
//  - gelu: exp2 constant folded (x2; t2=x*fma(C1,x2,C0); v_exp; rcp) -2 insts.

#define BATCH 16
#define SEQ 512
#define NVAR 64
#define DM 128
#define SEG 32
#define SCL 16
#define RNK 8
#define PRED 96
#define BN (BATCH * NVAR)   // 1024
#define ROWLEN (SEQ * DM)   // 65536

typedef unsigned short ushort_t;
typedef __attribute__((ext_vector_type(8))) short short8;   // 8 bf16
typedef __attribute__((ext_vector_type(4))) float f32x4;

__device__ inline float bf2f(ushort_t u) {
    union { unsigned int i; float f; } x;
    x.i = ((unsigned int)u) << 16;
    return x.f;
}
__device__ inline ushort_t f2bf(float f) {
    union { float f; unsigned int i; } u;
    u.f = f;
    unsigned int x = u.i;
    return (ushort_t)((x + 0x7fffu + ((x >> 16) & 1u)) >> 16);  // RNE
}
__device__ inline unsigned int pkbf(float a, float b) {  // packed bf16 pair
    __hip_bfloat162 h = __float22bfloat162_rn(make_float2(a, b));
    union { __hip_bfloat162 h2; unsigned int u; } c;
    c.h2 = h;
    return c.u;
}
__device__ inline float blo(unsigned int u) {
    union { unsigned int i; float f; } x;
    x.i = u << 16;
    return x.f;
}
__device__ inline float bhi(unsigned int u) {
    union { unsigned int i; float f; } x;
    x.i = u & 0xFFFF0000u;
    return x.f;
}
// gelu(x) = x * sigmoid(2t), t = 0.79788456*x*(1+0.044715*x^2).
// exp(-2t) = 2^(x*(C0 + C1*x^2)), C0 = -2*log2(e)*0.79788456, C1 = C0*0.044715.
__device__ inline float gelu_fast(float x) {
    float x2 = x * x;
    float t2 = x * fmaf(-0.10294854f, x2, -2.3022584f);
    float e;
    asm("v_exp_f32 %0, %1" : "=v"(e) : "v"(t2));
    return x * __builtin_amdgcn_rcpf(1.0f + e);
}

// ---------------- weight prep ----------------------------------------------
// bx in [0,3): layer-2 tap bx -> frag-major bf16 WTf (by=ci, tid=co).
// bx==3, by==0: rank-1 collapse of layer-1: A[k][co], Bias3[j][co].
__global__ __launch_bounds__(128) void wt_prep(
    const float* __restrict__ conv_w, const float* __restrict__ w_emb,
    const float* __restrict__ b_emb, const float* __restrict__ conv_b,
    ushort_t* __restrict__ WTf, float* __restrict__ Acoef,
    float* __restrict__ Bias3, float* __restrict__ regacc) {
    if (blockIdx.x == 0 && blockIdx.y == 0 && threadIdx.x == 0) regacc[0] = 0.f;
    if (blockIdx.x < 3) {
        int tap = blockIdx.x;   // layer-2 tap
        int ci = blockIdx.y;    // 0..127
        int co = threadIdx.x;   // 0..127
        int kt = ci >> 5, quad = (ci >> 3) & 3, j = ci & 7;
        int ng = co >> 4, col = co & 15;
        int lane = quad * 16 + col;
        WTf[((((size_t)tap * 4 + kt) * 8 + ng) * 64 + lane) * 8 + j] =
            f2bf(conv_w[(size_t)(3 + tap) * 16384 + (size_t)ci * 128 + co]);
    } else if (blockIdx.y == 0) {
        int co = threadIdx.x;
        float a0 = 0.f, a1 = 0.f, a2 = 0.f, c0 = 0.f, c1 = 0.f, c2 = 0.f;
        for (int ci = 0; ci < 128; ++ci) {
            float we = w_emb[ci], be = b_emb[ci];
            float w0 = conv_w[((size_t)(0 * 128 + ci)) * 128 + co];
            float w1 = conv_w[((size_t)(1 * 128 + ci)) * 128 + co];
            float w2 = conv_w[((size_t)(2 * 128 + ci)) * 128 + co];
            a0 += we * w0; c0 += be * w0;
            a1 += we * w1; c1 += be * w1;
            a2 += we * w2; c2 += be * w2;
        }
        Acoef[0 * 128 + co] = a0;
        Acoef[1 * 128 + co] = a1;
        Acoef[2 * 128 + co] = a2;
        float b0 = conv_b[co];
        Bias3[0 * 128 + co] = b0 + c2;             // l==0: only tap k=2 valid
        Bias3[1 * 128 + co] = b0 + c1 + c2;        // l==1: taps k=1,2 valid
        Bias3[2 * 128 + co] = b0 + c0 + c1 + c2;   // l>=2: all taps valid
    }
}

// ---------------- head_w half-transpose: f32 [k][p] -> bf16 frag-major ------
// For the kh half: tile k32p = s*32 + t (s=0..31, t=0..31) covers global
// k in [(s*64 + kh*32 + t)*32, +32). HWf[k32p*3072 + p*32 + kk] = bf16(w[k][p]).
__global__ __launch_bounds__(256) void hw_prep(
    const float* __restrict__ head_w, ushort_t* __restrict__ HWf, int kh) {
    __shared__ float ts[32 * 97];  // [kk][p], pad 97 vs bank conflicts
    int k32p = blockIdx.x;                    // 0..1023
    int s = k32p >> 5, t = k32p & 31;
    int kbase = (s * 64 + kh * 32 + t) * 32;  // global k of kk=0
    const float* src = head_w + (size_t)kbase * 96;
    for (int idx = threadIdx.x; idx < 3072; idx += 256) {
        int kk = idx / 96, p = idx - kk * 96;
        ts[kk * 97 + p] = src[idx];           // fully contiguous read
    }
    __syncthreads();
    unsigned int* ob32 =
        reinterpret_cast<unsigned int*>(HWf + (size_t)k32p * 3072);
    for (int odx = threadIdx.x; odx < 1536; odx += 256) {
        int p = odx >> 4, kk = (odx & 15) * 2;
        ob32[odx] = pkbf(ts[kk * 97 + p], ts[(kk + 1) * 97 + p]);
    }
}

// ---------------- fused TCN (layer1 scalar + layer2 MFMA) + z + e1/e2 ------
__global__ __launch_bounds__(256, 4) void tcn_mfma(
    const float* __restrict__ x, const float* __restrict__ w_emb,
    const float* __restrict__ b_emb, const float* __restrict__ Acoef,
    const float* __restrict__ Bias3, const ushort_t* __restrict__ WTf,
    const float* __restrict__ conv_b,
    const float* __restrict__ gw1, const float* __restrict__ gb1,
    const float* __restrict__ gw2, const float* __restrict__ gb2,
    ushort_t* __restrict__ h2, float* __restrict__ e1, float* __restrict__ e2) {
    __shared__ __align__(16) ushort_t h1s[68 * 136];  // h1, row = li+4; later
                                                      // rows 0..63 = staged h2
    __shared__ float xs[70];                          // x[l0-6 .. l0+63]
    __shared__ float zbuf[4 * 128];                   // segment means

    int bn = blockIdx.x;
    int b = bn >> 6, n = bn & 63;
    int chunk = blockIdx.y;
    int l0 = chunk * 64;
    int tid = threadIdx.x;

    // ---- stage x halo (broadcast scalars) ----
    {
        const float* xb = x + (size_t)b * SEQ * NVAR + n;
        if (tid < 70) {
            int l = l0 - 6 + tid;
            xs[tid] = (l >= 0) ? xb[(size_t)l * NVAR] : 0.0f;
        }
    }
    __syncthreads();

    // ---- layer 1 direct: h1[row][d] = gelu(sum_k x*A) + (x*we+be) ----
    {
        int dp = (tid & 63) * 2;
        float2 A0 = *reinterpret_cast<const float2*>(&Acoef[0 * 128 + dp]);
        float2 A1 = *reinterpret_cast<const float2*>(&Acoef[1 * 128 + dp]);
        float2 A2 = *reinterpret_cast<const float2*>(&Acoef[2 * 128 + dp]);
        float2 BF = *reinterpret_cast<const float2*>(&Bias3[2 * 128 + dp]);
        float2 we2 = *reinterpret_cast<const float2*>(&w_emb[dp]);
        float2 be2 = *reinterpret_cast<const float2*>(&b_emb[dp]);
#pragma unroll
        for (int i = 0; i < 17; ++i) {  // 68 rows x 64 pairs = 17*256
            int row = (tid >> 6) + 4 * i;   // wave-uniform
            int l = l0 - 4 + row;
            unsigned int pk = 0;
            if (l >= 0) {
                float x0 = xs[row], x1 = xs[row + 1], x2 = xs[row + 2];
                float2 bias = BF;
                if (l < 2)  // chunk 0, rows 4/5 only (wave-uniform)
                    bias = *reinterpret_cast<const float2*>(&Bias3[l * 128 + dp]);
                float y0 = fmaf(x0, A0.x, fmaf(x1, A1.x, fmaf(x2, A2.x, bias.x)));
                float y1 = fmaf(x0, A0.y, fmaf(x1, A1.y, fmaf(x2, A2.y, bias.y)));
                float r0 = gelu_fast(y0) + fmaf(x2, we2.x, be2.x);
                float r1 = gelu_fast(y1) + fmaf(x2, we2.y, be2.y);
                pk = pkbf(r0, r1);
            }
            *reinterpret_cast<unsigned int*>(&h1s[row * 136 + dp]) = pk;
        }
    }
    __syncthreads();

    int lane = tid & 63;
    int wv = tid >> 6;
    int quad = lane >> 4;
    int col = lane & 15;
    int cobase = wv * 32;

    // ---- layer 2 MFMA: li = mt*16+col; tap t reads h1s row li+2t ----
    f32x4 acc2[4][2];
#pragma unroll
    for (int mt = 0; mt < 4; ++mt)
#pragma unroll
        for (int nt = 0; nt < 2; ++nt)
            acc2[mt][nt] = (f32x4){0.f, 0.f, 0.f, 0.f};

#pragma unroll
    for (int tap = 0; tap < 3; ++tap) {
        short8 wf0[4], wf1[4];
#pragma unroll
        for (int kt = 0; kt < 4; ++kt) {
            const ushort_t* bp =
                WTf + ((((size_t)tap * 4 + kt) * 8 + wv * 2) * 64 + lane) * 8;
            wf0[kt] = *(const short8*)bp;
            wf1[kt] = *(const short8*)(bp + 512);
        }
#pragma unroll
        for (int kt = 0; kt < 4; ++kt) {
            int kc = kt * 32 + quad * 8;
#pragma unroll
            for (int mt = 0; mt < 4; ++mt) {
                short8 hf = *(const short8*)&h1s[(mt * 16 + col + 2 * tap) * 136 + kc];
                acc2[mt][0] = __builtin_amdgcn_mfma_f32_16x16x32_bf16(wf0[kt], hf, acc2[mt][0], 0, 0, 0);
                acc2[mt][1] = __builtin_amdgcn_mfma_f32_16x16x32_bf16(wf1[kt], hf, acc2[mt][1], 0, 0, 0);
            }
        }
    }

    // ---- epilogue 2: residuals -> regs, barrier, then stage h2 into h1s ----
    {
        uint2 res[4][2];
#pragma unroll
        for (int mt = 0; mt < 4; ++mt) {
            int li = mt * 16 + col;
#pragma unroll
            for (int nt = 0; nt < 2; ++nt) {
                int co = cobase + nt * 16 + quad * 4;
                res[mt][nt] = *reinterpret_cast<const uint2*>(
                    &h1s[(li + 4) * 136 + co]);
            }
        }
        __syncthreads();  // all h1 reads done; h1s rows 0..63 become h2 stage
        float4 bias[2];
        bias[0] = *reinterpret_cast<const float4*>(&conv_b[DM + cobase + quad * 4]);
        bias[1] = *reinterpret_cast<const float4*>(&conv_b[DM + cobase + 16 + quad * 4]);
#pragma unroll
        for (int mt = 0; mt < 4; ++mt) {
            int li = mt * 16 + col;
#pragma unroll
            for (int nt = 0; nt < 2; ++nt) {
                int co = cobase + nt * 16 + quad * 4;
                float h0 = gelu_fast(acc2[mt][nt][0] + bias[nt].x) + blo(res[mt][nt].x);
                float h1 = gelu_fast(acc2[mt][nt][1] + bias[nt].y) + bhi(res[mt][nt].x);
                float h2v = gelu_fast(acc2[mt][nt][2] + bias[nt].z) + blo(res[mt][nt].y);
                float h3 = gelu_fast(acc2[mt][nt][3] + bias[nt].w) + bhi(res[mt][nt].y);
                uint2 pk;
                pk.x = pkbf(h0, h1);
                pk.y = pkbf(h2v, h3);
                *reinterpret_cast<uint2*>(&h1s[li * 136 + co]) = pk;
            }
        }
    }
    __syncthreads();

    // ---- coalesced h2 store (from h1s rows 0..63) ----
    {
        ushort_t* orow = h2 + (size_t)bn * ROWLEN + (size_t)l0 * 128;
#pragma unroll
        for (int i = 0; i < 4; ++i) {
            int q = tid + 256 * i;
            int row = q >> 4, c8 = (q & 15) * 8;
            *(short8*)&orow[row * 128 + c8] = *(const short8*)&h1s[row * 136 + c8];
        }
    }
    // ---- z: 4 segment means over staged h2 tile ----
    {
        int d = tid & 127, sg = tid >> 7;
#pragma unroll
        for (int t = 0; t < 2; ++t) {
            int sl = sg + 2 * t;
            float a = 0.0f;
#pragma unroll
            for (int c = 0; c < SCL; ++c)
                a += bf2f(h1s[(sl * 16 + c) * 136 + d]);
            zbuf[sl * 128 + d] = a * (1.0f / 16.0f);
        }
    }
    __syncthreads();
    // ---- e1/e2: 64 outputs x 4-way d-split + shfl reduce ----
    {
        int out = tid >> 2;          // (sl, which, r)
        int part = tid & 3;          // d quarter
        int sl = out >> 4;
        int which = (out >> 3) & 1;
        int r = out & 7;
        const float* w = which ? gw2 : gw1;
        float a = 0.0f;
        int d0 = part * 32;
        for (int d = d0; d < d0 + 32; ++d)
            a += zbuf[sl * 128 + d] * w[d * RNK + r];
        a += __shfl_xor(a, 1, 64);
        a += __shfl_xor(a, 2, 64);
        if (part == 0) {
            a += (which ? gb2 : gb1)[r];
            int s = chunk * 4 + sl;
            (which ? e2 : e1)[(((size_t)b * SEG + s) * NVAR + n) * RNK + r] = a;
        }
    }
}

// ---------------- G GEMM (MFMA): B frags direct from HWf, As dbuf -----------
// Launched twice (kh=0 first=1 store; kh=1 first=0 read-add). grid (32,16).
__global__ __launch_bounds__(256) void g_gemm(
    const ushort_t* __restrict__ h2, const ushort_t* __restrict__ HWf,
    float* __restrict__ G, int kh, int first) {
    __shared__ __align__(16) ushort_t As[2][64 * 72];  // [buf][bn][k]
    int s = blockIdx.x;
    int bnt = blockIdx.y;
    int bn0 = bnt * 64;
    int kbase = kh * 1024;
    int lane = threadIdx.x & 63, wv = threadIdx.x >> 6;
    int quad = lane >> 4, col = lane & 15;
    int mh = wv & 1;   // bn half (32)
    int ph = wv >> 1;  // p half (48)
    int p0 = ph * 48 + col;

    int arow = threadIdx.x >> 2, akq = (threadIdx.x & 3) * 16;
    const ushort_t* aptr =
        h2 + (size_t)(bn0 + arow) * ROWLEN + (size_t)s * 2048 + kbase + akq;
    // B fragment base: frag(kt,kk,i) at hb + kt*6144 + kk*3072 + i*512
    const ushort_t* hb =
        HWf + (size_t)s * 98304 + (size_t)p0 * 32 + quad * 8;

    f32x4 acc[3][2];  // [p-tile][bn-tile]
#pragma unroll
    for (int i = 0; i < 3; ++i)
#pragma unroll
        for (int j = 0; j < 2; ++j) acc[i][j] = (f32x4){0.f, 0.f, 0.f, 0.f};

    // ---- prologue: stage As[0], load B frags for kt=0 ----
    short8 pa0 = *(const short8*)aptr;
    short8 pa1 = *(const short8*)(aptr + 8);
    short8 pf[2][2][3];  // [kt parity][kk][i]
#pragma unroll
    for (int kk = 0; kk < 2; ++kk)
#pragma unroll
        for (int i = 0; i < 3; ++i)
            pf[0][kk][i] = *(const short8*)(hb + kk * 3072 + i * 512);
    *(short8*)&As[0][arow * 72 + akq] = pa0;
    *(short8*)&As[0][arow * 72 + akq + 8] = pa1;
    __syncthreads();

#pragma unroll
    for (int kt = 0; kt < 16; ++kt) {
        const int par = kt & 1;
        if (kt < 15) {
            const ushort_t* ap = aptr + (kt + 1) * 64;
            pa0 = *(const short8*)ap;
            pa1 = *(const short8*)(ap + 8);
            const ushort_t* fb = hb + (size_t)(kt + 1) * 6144;
#pragma unroll
            for (int kk = 0; kk < 2; ++kk)
#pragma unroll
                for (int i = 0; i < 3; ++i)
                    pf[par ^ 1][kk][i] =
                        *(const short8*)(fb + kk * 3072 + i * 512);
        }
#pragma unroll
        for (int kk = 0; kk < 2; ++kk) {
            int kc = kk * 32 + quad * 8;
#pragma unroll
            for (int j = 0; j < 2; ++j) {
                short8 bnfr =
                    *(const short8*)&As[par][(mh * 32 + j * 16 + col) * 72 + kc];
#pragma unroll
                for (int i = 0; i < 3; ++i)
                    acc[i][j] = __builtin_amdgcn_mfma_f32_16x16x32_bf16(
                        pf[par][kk][i], bnfr, acc[i][j], 0, 0, 0);
            }
        }
        if (kt < 15) {
            *(short8*)&As[par ^ 1][arow * 72 + akq] = pa0;
            *(short8*)&As[par ^ 1][arow * 72 + akq + 8] = pa1;
        }
        __syncthreads();
    }

    // ---- G write: launch 0 stores, launch 1 read-adds (no atomics) ----
#pragma unroll
    for (int i = 0; i < 3; ++i)
#pragma unroll
        for (int j = 0; j < 2; ++j)
#pragma unroll
            for (int r = 0; r < 4; ++r) {
                int p = ph * 48 + i * 16 + quad * 4 + r;
                int m = mh * 32 + j * 16 + col;
                size_t o = (((size_t)s * BATCH + bnt) * PRED + p) * NVAR + m;
                if (first) G[o] = acc[i][j][r];
                else G[o] += acc[i][j][r];
            }
}

// ---------------- out partials (+ fused softmax + regularizer) --------------
__global__ __launch_bounds__(256) void out_partial(
    const float* __restrict__ e1, const float* __restrict__ e2,
    const float* __restrict__ G, float* __restrict__ partial,
    float* __restrict__ regacc) {
    __shared__ float adjn[2][32][65];
    __shared__ float Gs[96][65];
    __shared__ float e2s[3][64][8];
    __shared__ float e1s[3][32][8];
    __shared__ float wsum[4];
    int b = blockIdx.x, sg = blockIdx.y, nh = blockIdx.z;
    int s0 = sg * 2;
    int wv = threadIdx.x >> 6, lane = threadIdx.x & 63;

    // stage e1/e2 slices for s = s0-1, s0, s0+1 (zero-fill s<0)
    for (int idx = threadIdx.x; idx < 3 * 64 * 8; idx += 256) {
        int j = idx >> 9, m = (idx >> 3) & 63, r = idx & 7;
        int s = s0 - 1 + j;
        e2s[j][m][r] = (s >= 0)
            ? e2[(((size_t)b * SEG + s) * NVAR + m) * RNK + r] : 0.0f;
    }
    for (int idx = threadIdx.x; idx < 3 * 32 * 8; idx += 256) {
        int j = idx >> 8, nl = (idx >> 3) & 31, r = idx & 7;
        int s = s0 - 1 + j;
        e1s[j][nl][r] = (s >= 0)
            ? e1[(((size_t)b * SEG + s) * NVAR + nh * 32 + nl) * RNK + r] : 0.0f;
    }
    __syncthreads();

    // compute adj rows (lane = m); wave wv handles rows wv*8..wv*8+7
    float regsum = 0.0f;
    for (int t = 0; t < 8; ++t) {
        int nl = wv * 8 + t;
        float a[3];
#pragma unroll
        for (int j = 0; j < 3; ++j) {
            float sc = 0.0f;
#pragma unroll
            for (int r = 0; r < 8; ++r) sc += e1s[j][nl][r] * e2s[j][lane][r];
            sc *= 0.35355339059327373f;  // 1/sqrt(8)
            float mx = sc;
            for (int off = 32; off; off >>= 1)
                mx = fmaxf(mx, __shfl_xor(mx, off, 64));
            float ex = __expf(sc - mx);
            float sm = ex;
            for (int off = 32; off; off >>= 1) sm += __shfl_xor(sm, off, 64);
            a[j] = ex * __builtin_amdgcn_rcpf(sm);
        }
        if (s0 > 0) regsum += fabsf(a[1] - a[0]);  // diff at s0 (vs s0-1)
        regsum += fabsf(a[2] - a[1]);              // diff at s0+1 (vs s0)
        adjn[0][nl][lane] = a[1];
        adjn[1][nl][lane] = a[2];
    }
    __syncthreads();

    int pg = threadIdx.x >> 4;   // p = pg*6 + j
    int ng = threadIdx.x & 15;   // n = nh*32 + ng*2 + i
    float acc[6][2];
#pragma unroll
    for (int j = 0; j < 6; ++j) { acc[j][0] = 0.f; acc[j][1] = 0.f; }

#pragma unroll
    for (int ss = 0; ss < 2; ++ss) {
        int s = s0 + ss;
#pragma unroll
        for (int i = 0; i < 6; ++i) {
            int q = threadIdx.x + 256 * i;
            int row = q >> 4, mq = (q & 15) * 4;
            float4 v = *reinterpret_cast<const float4*>(
                &G[(((size_t)s * BATCH + b) * PRED + row) * NVAR + mq]);
            Gs[row][mq + 0] = v.x; Gs[row][mq + 1] = v.y;
            Gs[row][mq + 2] = v.z; Gs[row][mq + 3] = v.w;
        }
        __syncthreads();
#pragma unroll 4
        for (int m = 0; m < 64; ++m) {
            float a0 = adjn[ss][ng * 2 + 0][m];
            float a1 = adjn[ss][ng * 2 + 1][m];
#pragma unroll
            for (int j = 0; j < 6; ++j) {
                float g = Gs[pg * 6 + j][m];
                acc[j][0] += g * a0;
                acc[j][1] += g * a1;
            }
        }
        __syncthreads();
    }
#pragma unroll
    for (int j = 0; j < 6; ++j)
#pragma unroll
        for (int i = 0; i < 2; ++i) {
            int p = pg * 6 + j, n = nh * 32 + ng * 2 + i;
            partial[(((size_t)sg * BATCH + b) * PRED + p) * NVAR + n] = acc[j][i];
        }
    // block-reduce regsum -> one atomic
    for (int off = 32; off; off >>= 1) regsum += __shfl_xor(regsum, off, 64);
    if (lane == 0) wsum[wv] = regsum;
    __syncthreads();
    if (threadIdx.x == 0)
        atomicAdd(regacc, wsum[0] + wsum[1] + wsum[2] + wsum[3]);
}

// ---------------- reduce 16 partials + head_b (float4); write reg -----------
__global__ __launch_bounds__(256) void out_reduce(
    const float* __restrict__ partial, const float* __restrict__ head_b,
    const float* __restrict__ regacc, float* __restrict__ out, int out_size) {
    int i4 = blockIdx.x * 256 + threadIdx.x;  // 0..24575 float4s
    int p = (i4 >> 4) % PRED;
    float hb = head_b[p];
    float4 a = make_float4(hb, hb, hb, hb);
    const int stride4 = BATCH * PRED * NVAR / 4;
    const float4* p4 = reinterpret_cast<const float4*>(partial);
#pragma unroll
    for (int sg = 0; sg < 16; ++sg) {
        float4 v = p4[sg * stride4 + i4];
        a.x += v.x; a.y += v.y; a.z += v.z; a.w += v.w;
    }
    reinterpret_cast<float4*>(out)[i4] = a;
    if (i4 == 0) out[out_size - 1] = regacc[0] * (1.0f / 65536.0f);
}

extern "C" void kernel_launch(void* const* d_in, const int* in_sizes, int n_in,
                              void* d_out, int out_size, void* d_ws,
                              size_t ws_size, hipStream_t stream) {
    const float* x_enc  = (const float*)d_in[0];
    const float* w_emb  = (const float*)d_in[4];
    const float* b_emb  = (const float*)d_in[5];
    const float* conv_w = (const float*)d_in[6];
    const float* conv_b = (const float*)d_in[7];
    const float* gg_w1  = (const float*)d_in[8];
    const float* gg_b1  = (const float*)d_in[9];
    const float* gg_w2  = (const float*)d_in[10];
    const float* gg_b2  = (const float*)d_in[11];
    const float* head_w = (const float*)d_in[12];
    const float* head_b = (const float*)d_in[13];
    float* out = (float*)d_out;

    // workspace (157,286,404 B): HWf half (6.29 MB) fits in the 8.3 MB gap
    // between Bias3 and regacc; rebuilt per kh half (two g_gemm launches).
    char* ws = (char*)d_ws;
    ushort_t* h2   = (ushort_t*)(ws);                   // 134,217,728
    float* partial = (float*)(ws);                      //   6,291,456 (overlaps h2)
    float* G       = (float*)(ws + 134217728);          //  12,582,912
    float* e1      = (float*)(ws + 146800640);          //   1,048,576
    float* e2      = (float*)(ws + 147849216);          //   1,048,576
    ushort_t* WTf  = (ushort_t*)(ws + 148897792);       //      98,304
    float* Acoef   = (float*)(ws + 148996096);          //       1,536
    float* Bias3   = (float*)(ws + 148997632);          //       1,536
    ushort_t* HWf  = (ushort_t*)(ws + 149000192);       //   6,291,456 (half)
    float* regacc  = (float*)(ws + 157286400);          //           4

    wt_prep<<<dim3(4, 128), 128, 0, stream>>>(
        conv_w, w_emb, b_emb, conv_b, WTf, Acoef, Bias3, regacc);
    tcn_mfma<<<dim3(BN, SEQ / 64), 256, 0, stream>>>(
        x_enc, w_emb, b_emb, Acoef, Bias3, WTf, conv_b,
        gg_w1, gg_b1, gg_w2, gg_b2, h2, e1, e2);
    hw_prep<<<1024, 256, 0, stream>>>(head_w, HWf, 0);
    g_gemm<<<dim3(SEG, BATCH), 256, 0, stream>>>(h2, HWf, G, 0, 1);
    hw_prep<<<1024, 256, 0, stream>>>(head_w, HWf, 1);
    g_gemm<<<dim3(SEG, BATCH), 256, 0, stream>>>(h2, HWf, G, 1, 0);
    out_partial<<<dim3(BATCH, 16, 2), 256, 0, stream>>>(
        e1, e2, G, partial, regacc);
    out_reduce<<<BATCH * PRED * NVAR / 1024, 256, 0, stream>>>(
        partial, head_b, regacc, out, out_size);
}

// Round 3
// 290.430 us; speedup vs baseline: 1.2953x; 1.0230x over previous
//
#include <hip/hip_runtime.h>
#include <hip/hip_bf16.h>

// Model_81956565942963: TCN + low-rank dynamic graph + linear head.
// B=16, L=512, N=64, D=128, S=32 x 16, r=8, P=96. f32 in/out.
// R15:
//  - out_partial -> out_mix: atomicAdd per-sg contributions directly into out
//    (pre-init with head_b in prep). Kills the partial buffer (6.3 MB write +
//    100 MB re-read) and the out_reduce launch. fin<<<1,1>>> writes reg.
//  - prep = wt_prep + hw_prep(kh=0) + out-init in one launch (8 -> 7 launches).
//  - tcn: e1/e2 loop de-conflicted (zbuf stride 136 + part-interleaved d:
//    was 4-way same-bank every iter); z-phase vectorized (b32 pair reads,
//    one (sl,d-pair) per thread: 16 LDS + ~66 VALU vs 32 LDS + ~96 VALU).

#define BATCH 16
#define SEQ 512
#define NVAR 64
#define DM 128
#define SEG 32
#define SCL 16
#define RNK 8
#define PRED 96
#define BN (BATCH * NVAR)   // 1024
#define ROWLEN (SEQ * DM)   // 65536

typedef unsigned short ushort_t;
typedef __attribute__((ext_vector_type(8))) short short8;   // 8 bf16
typedef __attribute__((ext_vector_type(4))) float f32x4;

__device__ inline float bf2f(ushort_t u) {
    union { unsigned int i; float f; } x;
    x.i = ((unsigned int)u) << 16;
    return x.f;
}
__device__ inline ushort_t f2bf(float f) {
    union { float f; unsigned int i; } u;
    u.f = f;
    unsigned int x = u.i;
    return (ushort_t)((x + 0x7fffu + ((x >> 16) & 1u)) >> 16);  // RNE
}
__device__ inline unsigned int pkbf(float a, float b) {  // packed bf16 pair
    __hip_bfloat162 h = __float22bfloat162_rn(make_float2(a, b));
    union { __hip_bfloat162 h2; unsigned int u; } c;
    c.h2 = h;
    return c.u;
}
__device__ inline float blo(unsigned int u) {
    union { unsigned int i; float f; } x;
    x.i = u << 16;
    return x.f;
}
__device__ inline float bhi(unsigned int u) {
    union { unsigned int i; float f; } x;
    x.i = u & 0xFFFF0000u;
    return x.f;
}
// gelu(x) = x * sigmoid(2t), t = 0.79788456*x*(1+0.044715*x^2).
// exp(-2t) = 2^(x*(C0 + C1*x^2)), C0 = -2*log2(e)*0.79788456, C1 = C0*0.044715.
__device__ inline float gelu_fast(float x) {
    float x2 = x * x;
    float t2 = x * fmaf(-0.10294854f, x2, -2.3022584f);
    float e;
    asm("v_exp_f32 %0, %1" : "=v"(e) : "v"(t2));
    return x * __builtin_amdgcn_rcpf(1.0f + e);
}

// ---------------- prep: conv-weight prep + head_w half 0 + out init ---------
// blocks 0..511:    wt part (bx = bid>>7, ci = bid&127; 128 threads used)
// blocks 512..1535: hw part kh=0 (k32p = bid-512)
// blocks 1536..1919: out init: out[b][p][n] = head_b[p]
__global__ __launch_bounds__(256) void prep(
    const float* __restrict__ conv_w, const float* __restrict__ w_emb,
    const float* __restrict__ b_emb, const float* __restrict__ conv_b,
    const float* __restrict__ head_w, const float* __restrict__ head_b,
    ushort_t* __restrict__ WTf, float* __restrict__ Acoef,
    float* __restrict__ Bias3, ushort_t* __restrict__ HWf,
    float* __restrict__ out, float* __restrict__ regacc) {
    __shared__ float ts[32 * 97];
    int bid = blockIdx.x;
    if (bid == 0 && threadIdx.x == 0) regacc[0] = 0.f;
    if (bid < 512) {
        int bx = bid >> 7, ci = bid & 127;
        if (threadIdx.x < 128) {
            int co = threadIdx.x;
            if (bx < 3) {
                // layer-2 tap bx -> frag-major bf16
                int kt = ci >> 5, quad = (ci >> 3) & 3, j = ci & 7;
                int ng = co >> 4, col = co & 15;
                int lane = quad * 16 + col;
                WTf[((((size_t)bx * 4 + kt) * 8 + ng) * 64 + lane) * 8 + j] =
                    f2bf(conv_w[(size_t)(3 + bx) * 16384 + (size_t)ci * 128 + co]);
            } else if (ci == 0) {
                // rank-1 collapse of layer 1
                float a0 = 0.f, a1 = 0.f, a2 = 0.f, c0 = 0.f, c1 = 0.f, c2 = 0.f;
                for (int k = 0; k < 128; ++k) {
                    float we = w_emb[k], be = b_emb[k];
                    float w0 = conv_w[((size_t)(0 * 128 + k)) * 128 + co];
                    float w1 = conv_w[((size_t)(1 * 128 + k)) * 128 + co];
                    float w2 = conv_w[((size_t)(2 * 128 + k)) * 128 + co];
                    a0 += we * w0; c0 += be * w0;
                    a1 += we * w1; c1 += be * w1;
                    a2 += we * w2; c2 += be * w2;
                }
                Acoef[0 * 128 + co] = a0;
                Acoef[1 * 128 + co] = a1;
                Acoef[2 * 128 + co] = a2;
                float b0 = conv_b[co];
                Bias3[0 * 128 + co] = b0 + c2;
                Bias3[1 * 128 + co] = b0 + c1 + c2;
                Bias3[2 * 128 + co] = b0 + c0 + c1 + c2;
            }
        }
    } else if (bid < 1536) {
        // head_w f32 [k][p] -> bf16 frag-major, kh = 0
        int k32p = bid - 512;                 // 0..1023
        int s = k32p >> 5, t = k32p & 31;
        int kbase = (s * 64 + t) * 32;        // kh=0
        const float* src = head_w + (size_t)kbase * 96;
        for (int idx = threadIdx.x; idx < 3072; idx += 256) {
            int kk = idx / 96, p = idx - kk * 96;
            ts[kk * 97 + p] = src[idx];
        }
        __syncthreads();
        unsigned int* ob32 =
            reinterpret_cast<unsigned int*>(HWf + (size_t)k32p * 3072);
        for (int odx = threadIdx.x; odx < 1536; odx += 256) {
            int p = odx >> 4, kk = (odx & 15) * 2;
            ob32[odx] = pkbf(ts[kk * 97 + p], ts[(kk + 1) * 97 + p]);
        }
    } else {
        int idx = (bid - 1536) * 256 + threadIdx.x;
        if (idx < BATCH * PRED * NVAR) {
            int p = (idx >> 6) % PRED;
            out[idx] = head_b[p];
        }
    }
}

// ---------------- head_w half-transpose (kh=1 between the two g_gemms) ------
__global__ __launch_bounds__(256) void hw_prep(
    const float* __restrict__ head_w, ushort_t* __restrict__ HWf, int kh) {
    __shared__ float ts[32 * 97];
    int k32p = blockIdx.x;                    // 0..1023
    int s = k32p >> 5, t = k32p & 31;
    int kbase = (s * 64 + kh * 32 + t) * 32;
    const float* src = head_w + (size_t)kbase * 96;
    for (int idx = threadIdx.x; idx < 3072; idx += 256) {
        int kk = idx / 96, p = idx - kk * 96;
        ts[kk * 97 + p] = src[idx];
    }
    __syncthreads();
    unsigned int* ob32 =
        reinterpret_cast<unsigned int*>(HWf + (size_t)k32p * 3072);
    for (int odx = threadIdx.x; odx < 1536; odx += 256) {
        int p = odx >> 4, kk = (odx & 15) * 2;
        ob32[odx] = pkbf(ts[kk * 97 + p], ts[(kk + 1) * 97 + p]);
    }
}

// ---------------- fused TCN (layer1 scalar + layer2 MFMA) + z + e1/e2 ------
__global__ __launch_bounds__(256, 4) void tcn_mfma(
    const float* __restrict__ x, const float* __restrict__ w_emb,
    const float* __restrict__ b_emb, const float* __restrict__ Acoef,
    const float* __restrict__ Bias3, const ushort_t* __restrict__ WTf,
    const float* __restrict__ conv_b,
    const float* __restrict__ gw1, const float* __restrict__ gb1,
    const float* __restrict__ gw2, const float* __restrict__ gb2,
    ushort_t* __restrict__ h2, float* __restrict__ e1, float* __restrict__ e2) {
    __shared__ __align__(16) ushort_t h1s[68 * 136];  // h1, row = li+4; later
                                                      // rows 0..63 = staged h2
    __shared__ float xs[70];                          // x[l0-6 .. l0+63]
    __shared__ float zbuf[4 * 136];                   // segment means (pad 136)

    int bn = blockIdx.x;
    int b = bn >> 6, n = bn & 63;
    int chunk = blockIdx.y;
    int l0 = chunk * 64;
    int tid = threadIdx.x;

    // ---- stage x halo (broadcast scalars) ----
    {
        const float* xb = x + (size_t)b * SEQ * NVAR + n;
        if (tid < 70) {
            int l = l0 - 6 + tid;
            xs[tid] = (l >= 0) ? xb[(size_t)l * NVAR] : 0.0f;
        }
    }
    __syncthreads();

    // ---- layer 1 direct: h1[row][d] = gelu(sum_k x*A) + (x*we+be) ----
    {
        int dp = (tid & 63) * 2;
        float2 A0 = *reinterpret_cast<const float2*>(&Acoef[0 * 128 + dp]);
        float2 A1 = *reinterpret_cast<const float2*>(&Acoef[1 * 128 + dp]);
        float2 A2 = *reinterpret_cast<const float2*>(&Acoef[2 * 128 + dp]);
        float2 BF = *reinterpret_cast<const float2*>(&Bias3[2 * 128 + dp]);
        float2 we2 = *reinterpret_cast<const float2*>(&w_emb[dp]);
        float2 be2 = *reinterpret_cast<const float2*>(&b_emb[dp]);
#pragma unroll
        for (int i = 0; i < 17; ++i) {  // 68 rows x 64 pairs = 17*256
            int row = (tid >> 6) + 4 * i;   // wave-uniform
            int l = l0 - 4 + row;
            unsigned int pk = 0;
            if (l >= 0) {
                float x0 = xs[row], x1 = xs[row + 1], x2 = xs[row + 2];
                float2 bias = BF;
                if (l < 2)  // chunk 0, rows 4/5 only (wave-uniform)
                    bias = *reinterpret_cast<const float2*>(&Bias3[l * 128 + dp]);
                float y0 = fmaf(x0, A0.x, fmaf(x1, A1.x, fmaf(x2, A2.x, bias.x)));
                float y1 = fmaf(x0, A0.y, fmaf(x1, A1.y, fmaf(x2, A2.y, bias.y)));
                float r0 = gelu_fast(y0) + fmaf(x2, we2.x, be2.x);
                float r1 = gelu_fast(y1) + fmaf(x2, we2.y, be2.y);
                pk = pkbf(r0, r1);
            }
            *reinterpret_cast<unsigned int*>(&h1s[row * 136 + dp]) = pk;
        }
    }
    __syncthreads();

    int lane = tid & 63;
    int wv = tid >> 6;
    int quad = lane >> 4;
    int col = lane & 15;
    int cobase = wv * 32;

    // ---- layer 2 MFMA: li = mt*16+col; tap t reads h1s row li+2t ----
    f32x4 acc2[4][2];
#pragma unroll
    for (int mt = 0; mt < 4; ++mt)
#pragma unroll
        for (int nt = 0; nt < 2; ++nt)
            acc2[mt][nt] = (f32x4){0.f, 0.f, 0.f, 0.f};

#pragma unroll
    for (int tap = 0; tap < 3; ++tap) {
        short8 wf0[4], wf1[4];
#pragma unroll
        for (int kt = 0; kt < 4; ++kt) {
            const ushort_t* bp =
                WTf + ((((size_t)tap * 4 + kt) * 8 + wv * 2) * 64 + lane) * 8;
            wf0[kt] = *(const short8*)bp;
            wf1[kt] = *(const short8*)(bp + 512);
        }
#pragma unroll
        for (int kt = 0; kt < 4; ++kt) {
            int kc = kt * 32 + quad * 8;
#pragma unroll
            for (int mt = 0; mt < 4; ++mt) {
                short8 hf = *(const short8*)&h1s[(mt * 16 + col + 2 * tap) * 136 + kc];
                acc2[mt][0] = __builtin_amdgcn_mfma_f32_16x16x32_bf16(wf0[kt], hf, acc2[mt][0], 0, 0, 0);
                acc2[mt][1] = __builtin_amdgcn_mfma_f32_16x16x32_bf16(wf1[kt], hf, acc2[mt][1], 0, 0, 0);
            }
        }
    }

    // ---- epilogue 2: residuals -> regs, barrier, then stage h2 into h1s ----
    {
        uint2 res[4][2];
#pragma unroll
        for (int mt = 0; mt < 4; ++mt) {
            int li = mt * 16 + col;
#pragma unroll
            for (int nt = 0; nt < 2; ++nt) {
                int co = cobase + nt * 16 + quad * 4;
                res[mt][nt] = *reinterpret_cast<const uint2*>(
                    &h1s[(li + 4) * 136 + co]);
            }
        }
        __syncthreads();  // all h1 reads done; h1s rows 0..63 become h2 stage
        float4 bias[2];
        bias[0] = *reinterpret_cast<const float4*>(&conv_b[DM + cobase + quad * 4]);
        bias[1] = *reinterpret_cast<const float4*>(&conv_b[DM + cobase + 16 + quad * 4]);
#pragma unroll
        for (int mt = 0; mt < 4; ++mt) {
            int li = mt * 16 + col;
#pragma unroll
            for (int nt = 0; nt < 2; ++nt) {
                int co = cobase + nt * 16 + quad * 4;
                float h0 = gelu_fast(acc2[mt][nt][0] + bias[nt].x) + blo(res[mt][nt].x);
                float h1 = gelu_fast(acc2[mt][nt][1] + bias[nt].y) + bhi(res[mt][nt].x);
                float h2v = gelu_fast(acc2[mt][nt][2] + bias[nt].z) + blo(res[mt][nt].y);
                float h3 = gelu_fast(acc2[mt][nt][3] + bias[nt].w) + bhi(res[mt][nt].y);
                uint2 pk;
                pk.x = pkbf(h0, h1);
                pk.y = pkbf(h2v, h3);
                *reinterpret_cast<uint2*>(&h1s[li * 136 + co]) = pk;
            }
        }
    }
    __syncthreads();

    // ---- coalesced h2 store (from h1s rows 0..63) ----
    {
        ushort_t* orow = h2 + (size_t)bn * ROWLEN + (size_t)l0 * 128;
#pragma unroll
        for (int i = 0; i < 4; ++i) {
            int q = tid + 256 * i;
            int row = q >> 4, c8 = (q & 15) * 8;
            *(short8*)&orow[row * 128 + c8] = *(const short8*)&h1s[row * 136 + c8];
        }
    }
    // ---- z: 4 segment means; thread = (sl, d-pair), b32 reads ----
    {
        int sl = tid >> 6;
        int dp = (tid & 63) * 2;
        float a0 = 0.0f, a1 = 0.0f;
#pragma unroll
        for (int c = 0; c < SCL; ++c) {
            unsigned int u = *reinterpret_cast<const unsigned int*>(
                &h1s[(sl * 16 + c) * 136 + dp]);
            a0 += blo(u);
            a1 += bhi(u);
        }
        zbuf[sl * 136 + dp] = a0 * 0.0625f;
        zbuf[sl * 136 + dp + 1] = a1 * 0.0625f;
    }
    __syncthreads();
    // ---- e1/e2: 64 outputs x 4-way part-interleaved d + shfl reduce ----
    {
        int outi = tid >> 2;         // (sl, which, r)
        int part = tid & 3;          // d residue mod 4
        int sl = outi >> 4;
        int which = (outi >> 3) & 1;
        int r = outi & 7;
        const float* w = which ? gw2 : gw1;
        float a = 0.0f;
#pragma unroll 8
        for (int i = 0; i < 32; ++i) {
            int d = i * 4 + part;    // bank-conflict-free: 16 addrs, 16 banks
            a += zbuf[sl * 136 + d] * w[d * RNK + r];
        }
        a += __shfl_xor(a, 1, 64);
        a += __shfl_xor(a, 2, 64);
        if (part == 0) {
            a += (which ? gb2 : gb1)[r];
            int s = chunk * 4 + sl;
            (which ? e2 : e1)[(((size_t)b * SEG + s) * NVAR + n) * RNK + r] = a;
        }
    }
}

// ---------------- G GEMM (MFMA): B frags direct from HWf, As dbuf -----------
// Launched twice (kh=0 first=1 store; kh=1 first=0 read-add). grid (32,16).
__global__ __launch_bounds__(256) void g_gemm(
    const ushort_t* __restrict__ h2, const ushort_t* __restrict__ HWf,
    float* __restrict__ G, int kh, int first) {
    __shared__ __align__(16) ushort_t As[2][64 * 72];  // [buf][bn][k]
    int s = blockIdx.x;
    int bnt = blockIdx.y;
    int bn0 = bnt * 64;
    int kbase = kh * 1024;
    int lane = threadIdx.x & 63, wv = threadIdx.x >> 6;
    int quad = lane >> 4, col = lane & 15;
    int mh = wv & 1;   // bn half (32)
    int ph = wv >> 1;  // p half (48)
    int p0 = ph * 48 + col;

    int arow = threadIdx.x >> 2, akq = (threadIdx.x & 3) * 16;
    const ushort_t* aptr =
        h2 + (size_t)(bn0 + arow) * ROWLEN + (size_t)s * 2048 + kbase + akq;
    // B fragment base: frag(kt,kk,i) at hb + kt*6144 + kk*3072 + i*512
    const ushort_t* hb =
        HWf + (size_t)s * 98304 + (size_t)p0 * 32 + quad * 8;

    f32x4 acc[3][2];  // [p-tile][bn-tile]
#pragma unroll
    for (int i = 0; i < 3; ++i)
#pragma unroll
        for (int j = 0; j < 2; ++j) acc[i][j] = (f32x4){0.f, 0.f, 0.f, 0.f};

    // ---- prologue: stage As[0], load B frags for kt=0 ----
    short8 pa0 = *(const short8*)aptr;
    short8 pa1 = *(const short8*)(aptr + 8);
    short8 pf[2][2][3];  // [kt parity][kk][i]
#pragma unroll
    for (int kk = 0; kk < 2; ++kk)
#pragma unroll
        for (int i = 0; i < 3; ++i)
            pf[0][kk][i] = *(const short8*)(hb + kk * 3072 + i * 512);
    *(short8*)&As[0][arow * 72 + akq] = pa0;
    *(short8*)&As[0][arow * 72 + akq + 8] = pa1;
    __syncthreads();

#pragma unroll
    for (int kt = 0; kt < 16; ++kt) {
        const int par = kt & 1;
        if (kt < 15) {
            const ushort_t* ap = aptr + (kt + 1) * 64;
            pa0 = *(const short8*)ap;
            pa1 = *(const short8*)(ap + 8);
            const ushort_t* fb = hb + (size_t)(kt + 1) * 6144;
#pragma unroll
            for (int kk = 0; kk < 2; ++kk)
#pragma unroll
                for (int i = 0; i < 3; ++i)
                    pf[par ^ 1][kk][i] =
                        *(const short8*)(fb + kk * 3072 + i * 512);
        }
#pragma unroll
        for (int kk = 0; kk < 2; ++kk) {
            int kc = kk * 32 + quad * 8;
#pragma unroll
            for (int j = 0; j < 2; ++j) {
                short8 bnfr =
                    *(const short8*)&As[par][(mh * 32 + j * 16 + col) * 72 + kc];
#pragma unroll
                for (int i = 0; i < 3; ++i)
                    acc[i][j] = __builtin_amdgcn_mfma_f32_16x16x32_bf16(
                        pf[par][kk][i], bnfr, acc[i][j], 0, 0, 0);
            }
        }
        if (kt < 15) {
            *(short8*)&As[par ^ 1][arow * 72 + akq] = pa0;
            *(short8*)&As[par ^ 1][arow * 72 + akq + 8] = pa1;
        }
        __syncthreads();
    }

    // ---- G write: launch 0 stores, launch 1 read-adds (no atomics) ----
#pragma unroll
    for (int i = 0; i < 3; ++i)
#pragma unroll
        for (int j = 0; j < 2; ++j)
#pragma unroll
            for (int r = 0; r < 4; ++r) {
                int p = ph * 48 + i * 16 + quad * 4 + r;
                int m = mh * 32 + j * 16 + col;
                size_t o = (((size_t)s * BATCH + bnt) * PRED + p) * NVAR + m;
                if (first) G[o] = acc[i][j][r];
                else G[o] += acc[i][j][r];
            }
}

// ---------------- out mix: softmax + graph mixing, atomicAdd into out -------
__global__ __launch_bounds__(256) void out_mix(
    const float* __restrict__ e1, const float* __restrict__ e2,
    const float* __restrict__ G, float* __restrict__ out,
    float* __restrict__ regacc) {
    __shared__ float adjn[2][32][65];
    __shared__ float Gs[96][65];
    __shared__ float e2s[3][64][8];
    __shared__ float e1s[3][32][8];
    __shared__ float wsum[4];
    int b = blockIdx.x, sg = blockIdx.y, nh = blockIdx.z;
    int s0 = sg * 2;
    int wv = threadIdx.x >> 6, lane = threadIdx.x & 63;

    // stage e1/e2 slices for s = s0-1, s0, s0+1 (zero-fill s<0)
    for (int idx = threadIdx.x; idx < 3 * 64 * 8; idx += 256) {
        int j = idx >> 9, m = (idx >> 3) & 63, r = idx & 7;
        int s = s0 - 1 + j;
        e2s[j][m][r] = (s >= 0)
            ? e2[(((size_t)b * SEG + s) * NVAR + m) * RNK + r] : 0.0f;
    }
    for (int idx = threadIdx.x; idx < 3 * 32 * 8; idx += 256) {
        int j = idx >> 8, nl = (idx >> 3) & 31, r = idx & 7;
        int s = s0 - 1 + j;
        e1s[j][nl][r] = (s >= 0)
            ? e1[(((size_t)b * SEG + s) * NVAR + nh * 32 + nl) * RNK + r] : 0.0f;
    }
    __syncthreads();

    // compute adj rows (lane = m); wave wv handles rows wv*8..wv*8+7
    float regsum = 0.0f;
    for (int t = 0; t < 8; ++t) {
        int nl = wv * 8 + t;
        float a[3];
#pragma unroll
        for (int j = 0; j < 3; ++j) {
            float sc = 0.0f;
#pragma unroll
            for (int r = 0; r < 8; ++r) sc += e1s[j][nl][r] * e2s[j][lane][r];
            sc *= 0.35355339059327373f;  // 1/sqrt(8)
            float mx = sc;
            for (int off = 32; off; off >>= 1)
                mx = fmaxf(mx, __shfl_xor(mx, off, 64));
            float ex = __expf(sc - mx);
            float sm = ex;
            for (int off = 32; off; off >>= 1) sm += __shfl_xor(sm, off, 64);
            a[j] = ex * __builtin_amdgcn_rcpf(sm);
        }
        if (s0 > 0) regsum += fabsf(a[1] - a[0]);  // diff at s0 (vs s0-1)
        regsum += fabsf(a[2] - a[1]);              // diff at s0+1 (vs s0)
        adjn[0][nl][lane] = a[1];
        adjn[1][nl][lane] = a[2];
    }
    __syncthreads();

    int pg = threadIdx.x >> 4;   // p = pg*6 + j
    int ng = threadIdx.x & 15;   // n = nh*32 + ng*2 + i
    float acc[6][2];
#pragma unroll
    for (int j = 0; j < 6; ++j) { acc[j][0] = 0.f; acc[j][1] = 0.f; }

#pragma unroll
    for (int ss = 0; ss < 2; ++ss) {
        int s = s0 + ss;
#pragma unroll
        for (int i = 0; i < 6; ++i) {
            int q = threadIdx.x + 256 * i;
            int row = q >> 4, mq = (q & 15) * 4;
            float4 v = *reinterpret_cast<const float4*>(
                &G[(((size_t)s * BATCH + b) * PRED + row) * NVAR + mq]);
            Gs[row][mq + 0] = v.x; Gs[row][mq + 1] = v.y;
            Gs[row][mq + 2] = v.z; Gs[row][mq + 3] = v.w;
        }
        __syncthreads();
#pragma unroll 4
        for (int m = 0; m < 64; ++m) {
            float a0 = adjn[ss][ng * 2 + 0][m];
            float a1 = adjn[ss][ng * 2 + 1][m];
#pragma unroll
            for (int j = 0; j < 6; ++j) {
                float g = Gs[pg * 6 + j][m];
                acc[j][0] += g * a0;
                acc[j][1] += g * a1;
            }
        }
        __syncthreads();
    }
#pragma unroll
    for (int j = 0; j < 6; ++j)
#pragma unroll
        for (int i = 0; i < 2; ++i) {
            int p = pg * 6 + j, n = nh * 32 + ng * 2 + i;
            atomicAdd(&out[((size_t)b * PRED + p) * NVAR + n], acc[j][i]);
        }
    // block-reduce regsum -> one atomic
    for (int off = 32; off; off >>= 1) regsum += __shfl_xor(regsum, off, 64);
    if (lane == 0) wsum[wv] = regsum;
    __syncthreads();
    if (threadIdx.x == 0)
        atomicAdd(regacc, wsum[0] + wsum[1] + wsum[2] + wsum[3]);
}

// ---------------- fin: write regularizer scalar -----------------------------
__global__ void fin(const float* __restrict__ regacc, float* __restrict__ out,
                    int out_size) {
    out[out_size - 1] = regacc[0] * (1.0f / 65536.0f);
}

extern "C" void kernel_launch(void* const* d_in, const int* in_sizes, int n_in,
                              void* d_out, int out_size, void* d_ws,
                              size_t ws_size, hipStream_t stream) {
    const float* x_enc  = (const float*)d_in[0];
    const float* w_emb  = (const float*)d_in[4];
    const float* b_emb  = (const float*)d_in[5];
    const float* conv_w = (const float*)d_in[6];
    const float* conv_b = (const float*)d_in[7];
    const float* gg_w1  = (const float*)d_in[8];
    const float* gg_b1  = (const float*)d_in[9];
    const float* gg_w2  = (const float*)d_in[10];
    const float* gg_b2  = (const float*)d_in[11];
    const float* head_w = (const float*)d_in[12];
    const float* head_b = (const float*)d_in[13];
    float* out = (float*)d_out;

    // workspace (157,286,404 B): HWf half (6.29 MB) in the gap after Bias3;
    // rebuilt per kh half (prep does kh=0, hw_prep does kh=1).
    char* ws = (char*)d_ws;
    ushort_t* h2   = (ushort_t*)(ws);                   // 134,217,728
    float* G       = (float*)(ws + 134217728);          //  12,582,912
    float* e1      = (float*)(ws + 146800640);          //   1,048,576
    float* e2      = (float*)(ws + 147849216);          //   1,048,576
    ushort_t* WTf  = (ushort_t*)(ws + 148897792);       //      98,304
    float* Acoef   = (float*)(ws + 148996096);          //       1,536
    float* Bias3   = (float*)(ws + 148997632);          //       1,536
    ushort_t* HWf  = (ushort_t*)(ws + 149000192);       //   6,291,456 (half)
    float* regacc  = (float*)(ws + 157286400);          //           4

    prep<<<1920, 256, 0, stream>>>(
        conv_w, w_emb, b_emb, conv_b, head_w, head_b,
        WTf, Acoef, Bias3, HWf, out, regacc);
    tcn_mfma<<<dim3(BN, SEQ / 64), 256, 0, stream>>>(
        x_enc, w_emb, b_emb, Acoef, Bias3, WTf, conv_b,
        gg_w1, gg_b1, gg_w2, gg_b2, h2, e1, e2);
    g_gemm<<<dim3(SEG, BATCH), 256, 0, stream>>>(h2, HWf, G, 0, 1);
    hw_prep<<<1024, 256, 0, stream>>>(head_w, HWf, 1);
    g_gemm<<<dim3(SEG, BATCH), 256, 0, stream>>>(h2, HWf, G, 1, 0);
    out_mix<<<dim3(BATCH, 16, 2), 256, 0, stream>>>(
        e1, e2, G, out, regacc);
    fin<<<1, 1, 0, stream>>>(regacc, out, out_size);
}